// Round 3
// baseline (191.880 us; speedup 1.0000x reference)
//
#include <hip/hip_runtime.h>
#include <hip/hip_bf16.h>
#include <math.h>

#define BB 8
#define NN 2048
#define DD 1024
#define LL 128
#define MM (BB*NN)   // 16384

typedef _Float16 half8 __attribute__((ext_vector_type(8)));
typedef _Float16 half4 __attribute__((ext_vector_type(4)));
typedef __attribute__((ext_vector_type(4))) float floatx4;

__device__ __forceinline__ void glds16(const void* g, void* l) {
    __builtin_amdgcn_global_load_lds(
        (const __attribute__((address_space(1))) unsigned int*)g,
        (__attribute__((address_space(3))) unsigned int*)l, 16, 0, 0);
}

// fast tanh: 1 - 2/(e^{2x}+1); saturates correctly for |x| large, ~1e-6 abs err
__device__ __forceinline__ float ftanh(float x) {
    float e = __expf(2.0f * x);
    return 1.0f - 2.0f * __builtin_amdgcn_rcpf(e + 1.0f);
}

// ---------------- fused preprocessing: e_j -> fp16, Wk -> fp16, q = e_i @ Wq^T
__global__ __launch_bounds__(256) void prep_kernel(const float* __restrict__ e_j,
                                                   _Float16* __restrict__ eh,
                                                   const float* __restrict__ Wk,
                                                   _Float16* __restrict__ wh,
                                                   const float* __restrict__ e_i,
                                                   const float* __restrict__ Wq,
                                                   float* __restrict__ q) {
    __shared__ float us[BB][DD];   // 32 KB, used only by the q branch
    int blk = blockIdx.x;
    int tid = threadIdx.x;
    if (blk < 8192) {
        int i = blk * 256 + tid;
        const float4* xp = (const float4*)e_j + (size_t)i * 2;
        float4 v0 = xp[0], v1 = xp[1];
        half8 h;
        h[0] = (_Float16)v0.x; h[1] = (_Float16)v0.y;
        h[2] = (_Float16)v0.z; h[3] = (_Float16)v0.w;
        h[4] = (_Float16)v1.x; h[5] = (_Float16)v1.y;
        h[6] = (_Float16)v1.z; h[7] = (_Float16)v1.w;
        *(half8*)(eh + (size_t)i * 8) = h;
    } else if (blk < 8704) {
        int i = (blk - 8192) * 256 + tid;
        const float4* xp = (const float4*)Wk + (size_t)i * 2;
        float4 v0 = xp[0], v1 = xp[1];
        half8 h;
        h[0] = (_Float16)v0.x; h[1] = (_Float16)v0.y;
        h[2] = (_Float16)v0.z; h[3] = (_Float16)v0.w;
        h[4] = (_Float16)v1.x; h[5] = (_Float16)v1.y;
        h[6] = (_Float16)v1.z; h[7] = (_Float16)v1.w;
        *(half8*)(wh + (size_t)i * 8) = h;
    } else {
        for (int i = tid; i < BB * DD / 4; i += 256)
            ((float4*)&us[0][0])[i] = ((const float4*)e_i)[i];
        __syncthreads();
        int w = tid >> 6, lane = tid & 63;
        int d = (blk - 8704) * 4 + w;
        float acc[8] = {0.f, 0.f, 0.f, 0.f, 0.f, 0.f, 0.f, 0.f};
        for (int e0 = 0; e0 < DD; e0 += 256) {
            float4 wv = *(const float4*)&Wq[(size_t)d * DD + e0 + lane * 4];
            #pragma unroll
            for (int r = 0; r < 8; ++r) {
                float4 uv = *(const float4*)&us[r][e0 + lane * 4];
                acc[r] += wv.x * uv.x + wv.y * uv.y + wv.z * uv.z + wv.w * uv.w;
            }
        }
        #pragma unroll
        for (int r = 0; r < 8; ++r) {
            float s = acc[r];
            #pragma unroll
            for (int off = 32; off; off >>= 1) s += __shfl_down(s, off, 64);
            if (lane == 0) q[r * DD + d] = s;
        }
    }
}

// ---------------- sigma: 128x256 tile, 4 waves, TRIPLE-buffered BK=32, 2 blocks/CU.
// Cross-block TLP hides per-tile barrier/vmcnt/LDS-latency stalls: while one
// block waits, the co-resident block's waves issue MFMA on the same SIMDs.
// Per tile: vmcnt(6) | barrier | 12 ds_read_b128 + STAGE(t+2) | 32 MFMA.
__global__ __launch_bounds__(256, 2) void sigma128(const _Float16* __restrict__ eh,
                                                   const _Float16* __restrict__ wh,
                                                   const float* __restrict__ q,
                                                   const float* __restrict__ omega,
                                                   float* __restrict__ sig_part) // [4][MM]
{
    __shared__ _Float16 As[3][128][32];   // 24 KB (3 K-tile buffers)
    __shared__ _Float16 Bs[3][256][32];   // 48 KB

    const int tid  = threadIdx.x;
    const int lane = tid & 63;
    const int wid  = tid >> 6;          // 0..3
    const int wc   = wid;               // col-slice: 64 cols/wave
    const int c15  = lane & 15, quad = lane >> 4;

    // XCD-chunked bijective swizzle: 512 wgs, 64 per XCD
    const int wgid   = (blockIdx.x & 7) * 64 + (blockIdx.x >> 3);
    const int colBlk = wgid >> 7;        // 0..3
    const int rowBlk = wgid & 127;       // 0..127
    const int row0   = rowBlk * 128;
    const int col0   = colBlk * 256;
    const int b      = row0 / NN;

    // staging: linear LDS dest (glds16 requirement), swizzle folded into the
    // per-lane GLOBAL source column: sub = (lane&3) ^ ((lane>>3)&3)
    const int srow = wid * 16 + (lane >> 2);                 // 0..63
    const int ssub = ((lane & 3) ^ ((lane >> 3) & 3)) * 8;   // swizzled k-slot
    const _Float16* gA = eh + (size_t)(row0 + srow) * DD + ssub;
    const _Float16* gB = wh + (size_t)(col0 + srow) * DD + ssub;
    char* const ldsA0 = (char*)&As[0][0][0] + wid * 1024;
    char* const ldsB0 = (char*)&Bs[0][0][0] + wid * 1024;

// 6 glds16 per tile per wave: A rows {srow, srow+64}, B rows {srow,+64,+128,+192}
#define STAGE(kt, bi_) do { const int _k0 = (kt) * 32;                             \
        glds16(gA + _k0,                    ldsA0 + (bi_) * 8192);                 \
        glds16(gA + (size_t)64  * DD + _k0, ldsA0 + (bi_) * 8192  + 4096);         \
        glds16(gB + _k0,                    ldsB0 + (bi_) * 16384);                \
        glds16(gB + (size_t)64  * DD + _k0, ldsB0 + (bi_) * 16384 + 4096);         \
        glds16(gB + (size_t)128 * DD + _k0, ldsB0 + (bi_) * 16384 + 8192);         \
        glds16(gB + (size_t)192 * DD + _k0, ldsB0 + (bi_) * 16384 + 12288); } while (0)

    const char* const Abase = (const char*)&As[0][0][0];
    const char* const Bbase = (const char*)&Bs[0][0][0];
// swizzled fragment read: row stride 64B, XOR row bits 1-2 into the 16B slot
#define FRAGA(bi, row, qd) \
    (*(const half8*)(Abase + (bi) * 8192  + (row) * 64 + ((((qd) ^ (((row) >> 1) & 3))) << 4)))
#define FRAGB(bi, row, qd) \
    (*(const half8*)(Bbase + (bi) * 16384 + (row) * 64 + ((((qd) ^ (((row) >> 1) & 3))) << 4)))

    floatx4 acc[8][4];
    #pragma unroll
    for (int m = 0; m < 8; ++m)
        #pragma unroll
        for (int n = 0; n < 4; ++n) acc[m][n] = (floatx4){0.f, 0.f, 0.f, 0.f};

    // prologue: stage tiles 0,1 (12 vmem insts)
    STAGE(0, 0);
    STAGE(1, 1);

// vmcnt ledger: at tile t wait, issued = 12 + 6t insts (stages 0..t+1);
// vmcnt(6) => all but S(t+1) landed => tile t ready. Never drains to 0 mid-loop.
#define TILE(t_, bi_, DO_STAGE, VMW)                                               \
    {                                                                              \
        asm volatile("s_waitcnt vmcnt(" #VMW ")" ::: "memory");                    \
        __builtin_amdgcn_s_barrier();                                              \
        __builtin_amdgcn_sched_barrier(0);                                         \
        half8 a[8], bv[4];                                                         \
        _Pragma("unroll")                                                          \
        for (int n = 0; n < 4; ++n) bv[n] = FRAGB(bi_, wc * 64 + n * 16 + c15, quad); \
        _Pragma("unroll")                                                          \
        for (int m = 0; m < 8; ++m) a[m]  = FRAGA(bi_, m * 16 + c15, quad);        \
        if (DO_STAGE) STAGE((t_) + 2, ((t_) + 2) % 3);                             \
        __builtin_amdgcn_sched_barrier(0);                                         \
        __builtin_amdgcn_s_setprio(1);                                             \
        _Pragma("unroll")                                                          \
        for (int m = 0; m < 8; ++m)                                                \
            _Pragma("unroll")                                                      \
            for (int n = 0; n < 4; ++n)                                            \
                acc[m][n] = __builtin_amdgcn_mfma_f32_16x16x32_f16(a[m], bv[n], acc[m][n], 0, 0, 0); \
        __builtin_amdgcn_s_setprio(0);                                             \
    }

    // steady state: tiles 0..29 stage tiles 2..31 (3-tile groups keep bi literal)
    for (int tt = 0; tt < 30; tt += 3) {
        TILE(tt + 0, 0, 1, 6)
        TILE(tt + 1, 1, 1, 6)
        TILE(tt + 2, 2, 1, 6)
    }
    TILE(30, 0, 0, 6)
    TILE(31, 1, 0, 0)

#undef TILE
#undef FRAGA
#undef FRAGB
#undef STAGE

    // ---- fused epilogue: part[row] = sum_n tanh(acc+q)*omega over this wave's 64 cols
    float part[8][4];
    #pragma unroll
    for (int m = 0; m < 8; ++m)
        #pragma unroll
        for (int r = 0; r < 4; ++r) part[m][r] = 0.f;

    #pragma unroll
    for (int n = 0; n < 4; ++n) {
        int col = col0 + wc * 64 + n * 16 + c15;
        float qv = q[b * DD + col];
        float om = omega[col];
        #pragma unroll
        for (int m = 0; m < 8; ++m)
            #pragma unroll
            for (int r = 0; r < 4; ++r)
                part[m][r] += ftanh(acc[m][n][r] + qv) * om;
    }

    float (*red)[4] = (float(*)[4])&As[0][0][0];   // 2 KB, reuse dead A-buffer 0
    #pragma unroll
    for (int m = 0; m < 8; ++m)
        #pragma unroll
        for (int r = 0; r < 4; ++r) {
            float s = part[m][r];
            s += __shfl_xor(s, 1, 64);
            s += __shfl_xor(s, 2, 64);
            s += __shfl_xor(s, 4, 64);
            s += __shfl_xor(s, 8, 64);
            if (c15 == 0) red[m * 16 + quad * 4 + r][wc] = s;
        }
    __syncthreads();
    if (tid < 128)
        sig_part[(size_t)colBlk * MM + row0 + tid] =
            red[tid][0] + red[tid][1] + red[tid][2] + red[tid][3];
}

// ---------------- per-b softmax-style weights (64 blocks: 8 per b, full stats each)
__global__ __launch_bounds__(256) void softmax_k(const float* __restrict__ sig_part,
                                                 const float* __restrict__ imp,
                                                 float* __restrict__ a_ij) {
    int b = blockIdx.x >> 3, slice = blockIdx.x & 7;
    int tid = threadIdx.x;
    __shared__ float red[256];
    float sv[8];
    float m = -1e30f;
    #pragma unroll
    for (int p = 0; p < 8; ++p) {
        int n = p * 256 + tid;
        float s = 0.f;
        #pragma unroll
        for (int db = 0; db < 4; ++db) s += sig_part[db * MM + b * NN + n];
        sv[p] = s;
        m = fmaxf(m, s);
    }
    red[tid] = m; __syncthreads();
    for (int off = 128; off; off >>= 1) {
        if (tid < off) red[tid] = fmaxf(red[tid], red[tid + off]);
        __syncthreads();
    }
    m = red[0]; __syncthreads();
    float sum = 0.f;
    #pragma unroll
    for (int p = 0; p < 8; ++p) sum += expf(sv[p] - m);
    red[tid] = sum; __syncthreads();
    for (int off = 128; off; off >>= 1) {
        if (tid < off) red[tid] += red[tid + off];
        __syncthreads();
    }
    float inv = 1.f / (red[0] + 1e-9f * expf(-m));
    int n = slice * 256 + tid;
    a_ij[b * NN + n] = imp[b * NN + n] * expf(sv[slice] - m) * inv;
}

// ---------------- u partials from fp16 e_j: 1024 blocks, disjoint writes
__global__ __launch_bounds__(256) void u_kernel(const float* __restrict__ a_ij,
                                                const _Float16* __restrict__ eh,
                                                float* __restrict__ u_part) {
    int b = blockIdx.x >> 7, nc = blockIdx.x & 127;
    int t = threadIdx.x;
    float4 acc = {0.f, 0.f, 0.f, 0.f};
    const _Float16* base = eh + ((size_t)(b * NN + nc * 16)) * DD + t * 4;
    const float* ap = a_ij + b * NN + nc * 16;
    #pragma unroll
    for (int n = 0; n < 16; ++n) {
        float a = ap[n];
        half4 v = *(const half4*)(base + (size_t)n * DD);
        acc.x += a * (float)v[0]; acc.y += a * (float)v[1];
        acc.z += a * (float)v[2]; acc.w += a * (float)v[3];
    }
    *(float4*)(u_part + ((size_t)nc * BB + b) * DD + t * 4) = acc;
}

// ---------------- u[b,e] = sum over 128 partials
__global__ __launch_bounds__(256) void ureduce(const float* __restrict__ u_part,
                                               float* __restrict__ u) {
    int i = blockIdx.x * 256 + threadIdx.x;   // < 8192
    float s = 0.f;
    #pragma unroll 8
    for (int nc = 0; nc < 128; ++nc) s += u_part[(size_t)nc * BB * DD + i];
    u[i] = s;
}

// ---------------- A = X @ W^T with X cached in LDS; W read once (256 blocks)
__global__ __launch_bounds__(256) void rowdot8(const float* __restrict__ X,
                                               const float* __restrict__ W,
                                               float* __restrict__ out) {
    __shared__ float us[BB][DD];
    int tid = threadIdx.x;
    for (int i = tid; i < BB * DD / 4; i += 256)
        ((float4*)&us[0][0])[i] = ((const float4*)X)[i];
    __syncthreads();
    int w = tid >> 6, lane = tid & 63;
    int d = blockIdx.x * 4 + w;
    float acc[8] = {0.f, 0.f, 0.f, 0.f, 0.f, 0.f, 0.f, 0.f};
    for (int e0 = 0; e0 < DD; e0 += 256) {
        float4 wv = *(const float4*)&W[(size_t)d * DD + e0 + lane * 4];
        #pragma unroll
        for (int r = 0; r < 8; ++r) {
            float4 uv = *(const float4*)&us[r][e0 + lane * 4];
            acc[r] += wv.x * uv.x + wv.y * uv.y + wv.z * uv.z + wv.w * uv.w;
        }
    }
    #pragma unroll
    for (int r = 0; r < 8; ++r) {
        float s = acc[r];
        #pragma unroll
        for (int off = 32; off; off >>= 1) s += __shfl_down(s, off, 64);
        if (lane == 0) out[r * DD + d] = s;
    }
}

// ---------------- outputs: A, A_lk = A*R, A_l = A
__global__ __launch_bounds__(256) void out_kernel(const float* __restrict__ A,
                                                  const float* __restrict__ Rlk,
                                                  float* __restrict__ out) {
    int i = blockIdx.x * 256 + threadIdx.x;
    int d = i & (DD - 1);
    int l = (i >> 10) & (LL - 1);
    int b = i >> 17;
    out[BB * DD + i] = A[b * DD + d] * Rlk[l * DD + d];
    if (i < BB * DD) {
        out[i] = A[i];
        out[BB * DD + BB * LL * DD + i] = A[i];
    }
}

extern "C" void kernel_launch(void* const* d_in, const int* in_sizes, int n_in,
                              void* d_out, int out_size, void* d_ws, size_t ws_size,
                              hipStream_t stream) {
    const float* e_i   = (const float*)d_in[0];
    const float* e_j   = (const float*)d_in[1];
    const float* imp   = (const float*)d_in[2];
    const float* Rlk   = (const float*)d_in[3];
    const float* Wq    = (const float*)d_in[4];
    const float* Wk    = (const float*)d_in[5];
    const float* Wv    = (const float*)d_in[6];
    const float* omega = (const float*)d_in[7];
    float* out = (float*)d_out;
    float* ws  = (float*)d_ws;

    float* q    = ws;               // 8192
    float* sigp = ws + 8192;        // 65536 used (region holds 131072)
    float* a_ij = ws + 139264;      // 16384 (head reused as Abuf)
    float* u    = ws + 155648;      // 8192
    _Float16* eh = (_Float16*)(ws + 172032);      // MM*DD halfs = 32 MB
    _Float16* wh = eh + (size_t)MM * DD;          // 2 MB
    float* u_part = (float*)(wh + (size_t)DD * DD);  // 4 MB

    // 1) e_j -> fp16, Wk -> fp16, q = e_i @ Wq^T (Wq read once)
    prep_kernel<<<8960, 256, 0, stream>>>(e_j, eh, Wk, wh, e_i, Wq, q);

    // 2) sigma partials: 128x256-tile, 2 blocks/CU, triple-buffered counted-vmcnt
    sigma128<<<dim3(512), 256, 0, stream>>>(eh, wh, q, omega, sigp);

    // 3) a_ij
    softmax_k<<<64, 256, 0, stream>>>(sigp, imp, a_ij);

    // 4) u partials (no atomics) from fp16 e_j, then reduce
    u_kernel<<<1024, 256, 0, stream>>>(a_ij, eh, u_part);
    ureduce<<<32, 256, 0, stream>>>(u_part, u);

    // 5) A = u @ Wv^T (Wv read once; Abuf = a_ij head)
    rowdot8<<<256, 256, 0, stream>>>(u, Wv, a_ij);

    // 6) outputs
    out_kernel<<<(BB * LL * DD) / 256, 256, 0, stream>>>(a_ij, Rlk, out);
}

// Round 4
// 185.013 us; speedup vs baseline: 1.0371x; 1.0371x over previous
//
#include <hip/hip_runtime.h>
#include <hip/hip_bf16.h>
#include <math.h>

#define BB 8
#define NN 2048
#define DD 1024
#define LL 128
#define MM (BB*NN)   // 16384

typedef _Float16 half8 __attribute__((ext_vector_type(8)));
typedef _Float16 half4 __attribute__((ext_vector_type(4)));
typedef __attribute__((ext_vector_type(4))) float floatx4;

__device__ __forceinline__ void glds16(const void* g, void* l) {
    __builtin_amdgcn_global_load_lds(
        (const __attribute__((address_space(1))) unsigned int*)g,
        (__attribute__((address_space(3))) unsigned int*)l, 16, 0, 0);
}

// fast tanh: 1 - 2/(e^{2x}+1); saturates correctly for |x| large, ~1e-6 abs err
__device__ __forceinline__ float ftanh(float x) {
    float e = __expf(2.0f * x);
    return 1.0f - 2.0f * __builtin_amdgcn_rcpf(e + 1.0f);
}

// ---------------- fused preprocessing: e_j -> fp16, Wk -> fp16, q = e_i @ Wq^T
__global__ __launch_bounds__(256) void prep_kernel(const float* __restrict__ e_j,
                                                   _Float16* __restrict__ eh,
                                                   const float* __restrict__ Wk,
                                                   _Float16* __restrict__ wh,
                                                   const float* __restrict__ e_i,
                                                   const float* __restrict__ Wq,
                                                   float* __restrict__ q) {
    __shared__ float us[BB][DD];   // 32 KB, used only by the q branch
    int blk = blockIdx.x;
    int tid = threadIdx.x;
    if (blk < 8192) {
        int i = blk * 256 + tid;
        const float4* xp = (const float4*)e_j + (size_t)i * 2;
        float4 v0 = xp[0], v1 = xp[1];
        half8 h;
        h[0] = (_Float16)v0.x; h[1] = (_Float16)v0.y;
        h[2] = (_Float16)v0.z; h[3] = (_Float16)v0.w;
        h[4] = (_Float16)v1.x; h[5] = (_Float16)v1.y;
        h[6] = (_Float16)v1.z; h[7] = (_Float16)v1.w;
        *(half8*)(eh + (size_t)i * 8) = h;
    } else if (blk < 8704) {
        int i = (blk - 8192) * 256 + tid;
        const float4* xp = (const float4*)Wk + (size_t)i * 2;
        float4 v0 = xp[0], v1 = xp[1];
        half8 h;
        h[0] = (_Float16)v0.x; h[1] = (_Float16)v0.y;
        h[2] = (_Float16)v0.z; h[3] = (_Float16)v0.w;
        h[4] = (_Float16)v1.x; h[5] = (_Float16)v1.y;
        h[6] = (_Float16)v1.z; h[7] = (_Float16)v1.w;
        *(half8*)(wh + (size_t)i * 8) = h;
    } else {
        for (int i = tid; i < BB * DD / 4; i += 256)
            ((float4*)&us[0][0])[i] = ((const float4*)e_i)[i];
        __syncthreads();
        int w = tid >> 6, lane = tid & 63;
        int d = (blk - 8704) * 4 + w;
        float acc[8] = {0.f, 0.f, 0.f, 0.f, 0.f, 0.f, 0.f, 0.f};
        for (int e0 = 0; e0 < DD; e0 += 256) {
            float4 wv = *(const float4*)&Wq[(size_t)d * DD + e0 + lane * 4];
            #pragma unroll
            for (int r = 0; r < 8; ++r) {
                float4 uv = *(const float4*)&us[r][e0 + lane * 4];
                acc[r] += wv.x * uv.x + wv.y * uv.y + wv.z * uv.z + wv.w * uv.w;
            }
        }
        #pragma unroll
        for (int r = 0; r < 8; ++r) {
            float s = acc[r];
            #pragma unroll
            for (int off = 32; off; off >>= 1) s += __shfl_down(s, off, 64);
            if (lane == 0) q[r * DD + d] = s;
        }
    }
}

// ---------------- sigma: faithful m201 8-phase port. 256x256 tile, 8 waves (2Mx4N),
// BK=64, 2 K-tiles/iter, LDS [2slot][2half][128][64] per matrix (128 KB total).
// Per phase: {ds_reads | stage 1 half-tile | bar | lgkm0 | 16 MFMA | bar};
// vmcnt(4) only at phases 4 and 8 (counted, never drained mid-loop).
__global__ __launch_bounds__(512, 2) void sigma256(const _Float16* __restrict__ eh,
                                                   const _Float16* __restrict__ wh,
                                                   const float* __restrict__ q,
                                                   const float* __restrict__ omega,
                                                   float* __restrict__ sig_part) // [4][MM]
{
    __shared__ _Float16 As[2][2][128][64];   // [slot][half] 64 KB
    __shared__ _Float16 Bs[2][2][128][64];   // 64 KB

    const int tid  = threadIdx.x;
    const int lane = tid & 63;
    const int wid  = tid >> 6;          // 0..7
    const int wm   = wid >> 2;          // 0..1 : A half / 128-row block
    const int wn   = wid & 3;           // 0..3 : 64-col block
    const int c15  = lane & 15, quad = lane >> 4;

    // XCD-chunked bijective swizzle: 256 wgs, 32 per XCD
    const int wgid   = (blockIdx.x & 7) * 32 + (blockIdx.x >> 3);
    const int colBlk = wgid >> 6;        // 0..3
    const int rowBlk = wgid & 63;        // 0..63
    const int row0   = rowBlk * 256;
    const int col0   = colBlk * 256;
    const int b      = row0 / NN;

    // ---- staging: linear LDS dest, 8-way XOR swizzle folded into global source.
    // lane l covers (row = wid*16 + (l>>3) [+8 for 2nd inst], qslot' = l&7);
    // data for qslot q = (l&7) ^ (l>>3)  [row&7 == l>>3 for both insts]
    const int l3  = lane >> 3;
    const int qst = ((lane & 7) ^ l3) * 8;     // halfs
    const _Float16* gA = eh + (size_t)(row0 + wid * 16 + l3) * DD + qst;
    const _Float16* gB = wh + (size_t)(col0 + wid * 16 + l3) * DD + qst;
    char* const ldsA = (char*)&As[0][0][0][0] + wid * 2048;
    char* const ldsB = (char*)&Bs[0][0][0][0] + wid * 2048;

#define STG_A(kt, hf, s) do { \
    glds16(gA + (size_t)(hf) * 128 * DD + (kt) * 64,          ldsA + (s) * 32768 + (hf) * 16384); \
    glds16(gA + (size_t)(hf) * 128 * DD + (kt) * 64 + 8 * DD, ldsA + (s) * 32768 + (hf) * 16384 + 1024); } while (0)
#define STG_B(kt, hf, s) do { \
    glds16(gB + (size_t)(hf) * 128 * DD + (kt) * 64,          ldsB + (s) * 32768 + (hf) * 16384); \
    glds16(gB + (size_t)(hf) * 128 * DD + (kt) * 64 + 8 * DD, ldsB + (s) * 32768 + (hf) * 16384 + 1024); } while (0)

    // ---- swizzled fragment reads: row stride 128B, q' = q ^ (row&7), row&7 == c15&7
    const int swz = c15 & 7;
    const int q0  = (quad ^ swz) << 4;
    const int q1  = ((4 + quad) ^ swz) << 4;
    const char* const afp = (const char*)&As[0][0][0][0] + wm * 16384 + c15 * 128;
    const char* const bfp = (const char*)&Bs[0][0][0][0] + (wn >> 1) * 16384
                            + ((wn & 1) * 64 + c15) * 128;
#define FA(s, m, ks) (*(const half8*)(afp + (s) * 32768 + (m) * 2048 + ((ks) ? q1 : q0)))
#define FB(s, n, ks) (*(const half8*)(bfp + (s) * 32768 + (n) * 2048 + ((ks) ? q1 : q0)))

    floatx4 acc[8][4];
    #pragma unroll
    for (int m = 0; m < 8; ++m)
        #pragma unroll
        for (int n = 0; n < 4; ++n) acc[m][n] = (floatx4){0.f, 0.f, 0.f, 0.f};

    half8 a[8], bl[4], bh[4];

#define BARx()  __builtin_amdgcn_s_barrier()
#define SBARx() __builtin_amdgcn_sched_barrier(0)
#define LGKM0() asm volatile("s_waitcnt lgkmcnt(0)" ::: "memory")
#define MFMA16(MB, NB, BARR) \
    __builtin_amdgcn_s_setprio(1); \
    _Pragma("unroll") for (int m_ = 0; m_ < 4; ++m_) \
    _Pragma("unroll") for (int n_ = 0; n_ < 2; ++n_) \
    _Pragma("unroll") for (int ks_ = 0; ks_ < 2; ++ks_) \
        acc[(MB) + m_][(NB) + n_] = __builtin_amdgcn_mfma_f32_16x16x32_f16( \
            a[m_ * 2 + ks_], BARR[n_ * 2 + ks_], acc[(MB) + m_][(NB) + n_], 0, 0, 0); \
    __builtin_amdgcn_s_setprio(0);

// ph type A: 12 reads (a m0-3, bl n0-1), MFMA acc[0-3][0-1]
#define PH_A(s, STAGE) \
    _Pragma("unroll") for (int m_ = 0; m_ < 4; ++m_) { a[m_*2] = FA(s, m_, 0); a[m_*2+1] = FA(s, m_, 1); } \
    _Pragma("unroll") for (int n_ = 0; n_ < 2; ++n_) { bl[n_*2] = FB(s, n_, 0); bl[n_*2+1] = FB(s, n_, 1); } \
    STAGE; SBARx(); BARx(); LGKM0(); SBARx(); MFMA16(0, 0, bl) BARx();
// ph type B: 4 reads (bh n2-3), MFMA acc[0-3][2-3]
#define PH_B(s, STAGE) \
    _Pragma("unroll") for (int n_ = 0; n_ < 2; ++n_) { bh[n_*2] = FB(s, 2+n_, 0); bh[n_*2+1] = FB(s, 2+n_, 1); } \
    STAGE; SBARx(); BARx(); LGKM0(); SBARx(); MFMA16(0, 2, bh) BARx();
// ph type C: 8 reads (a m4-7), MFMA acc[4-7][0-1]
#define PH_C(s, STAGE) \
    _Pragma("unroll") for (int m_ = 0; m_ < 4; ++m_) { a[m_*2] = FA(s, 4+m_, 0); a[m_*2+1] = FA(s, 4+m_, 1); } \
    STAGE; SBARx(); BARx(); LGKM0(); SBARx(); MFMA16(4, 0, bl) BARx();
// ph type D: 0 reads, MFMA acc[4-7][2-3], counted vmcnt before closing barrier
#define PH_D(s, STAGE, VMW) \
    STAGE; SBARx(); BARx(); LGKM0(); SBARx(); MFMA16(4, 2, bh) \
    asm volatile("s_waitcnt vmcnt(" VMW ")" ::: "memory"); BARx();

    // prologue: tile0 complete + tile1 B halves = 12 insts; vmcnt(4) => tile0 landed
    STG_A(0, 0, 0); STG_A(0, 1, 0); STG_B(0, 0, 0); STG_B(0, 1, 0);
    STG_B(1, 0, 1); STG_B(1, 1, 1);
    asm volatile("s_waitcnt vmcnt(4)" ::: "memory");
    BARx();

    // steady state: iter i processes K-tiles 2i (slot0), 2i+1 (slot1).
    // Stage schedule (each target's last read is barrier-certified complete):
    // ph1:A0(2i+1) ph2:A1(2i+1) ph3:B0(2i+2) ph4:B1(2i+2)+vmcnt(4)
    // ph5:A0(2i+2) ph6:A1(2i+2) ph7:B0(2i+3) ph8:B1(2i+3)+vmcnt(4)
    for (int i = 0; i < 7; ++i) {
        const int k1 = 2 * i + 1, k2 = 2 * i + 2, k3 = 2 * i + 3;
        PH_A(0, STG_A(k1, 0, 1))
        PH_B(0, STG_A(k1, 1, 1))
        PH_C(0, STG_B(k2, 0, 0))
        PH_D(0, STG_B(k2, 1, 0), "4")
        PH_A(1, STG_A(k2, 0, 0))
        PH_B(1, STG_A(k2, 1, 0))
        PH_C(1, STG_B(k3, 0, 1))
        PH_D(1, STG_B(k3, 1, 1), "4")
    }
    // last iter: tiles 14,15; only tile-15 A halves remain to stage
    PH_A(0, STG_A(15, 0, 1))
    PH_B(0, STG_A(15, 1, 1))
    PH_C(0, ((void)0))
    PH_D(0, ((void)0), "0")
    PH_A(1, ((void)0))
    PH_B(1, ((void)0))
    PH_C(1, ((void)0))
    PH_D(1, ((void)0), "0")

#undef PH_A
#undef PH_B
#undef PH_C
#undef PH_D
#undef MFMA16
#undef FA
#undef FB
#undef STG_A
#undef STG_B

    // ---- fused epilogue: part[row] = sum_cols tanh(acc+q)*omega (this wave's 64 cols)
    float part[8][4];
    #pragma unroll
    for (int m = 0; m < 8; ++m)
        #pragma unroll
        for (int r = 0; r < 4; ++r) part[m][r] = 0.f;

    #pragma unroll
    for (int n = 0; n < 4; ++n) {
        int col = col0 + wn * 64 + n * 16 + c15;
        float qv = q[b * DD + col];
        float om = omega[col];
        #pragma unroll
        for (int m = 0; m < 8; ++m)
            #pragma unroll
            for (int r = 0; r < 4; ++r)
                part[m][r] += ftanh(acc[m][n][r] + qv) * om;
    }

    float (*red)[4] = (float(*)[4])&As[0][0][0][0];   // [256][4] = 4 KB, As is dead
    #pragma unroll
    for (int m = 0; m < 8; ++m)
        #pragma unroll
        for (int r = 0; r < 4; ++r) {
            float s = part[m][r];
            s += __shfl_xor(s, 1, 64);
            s += __shfl_xor(s, 2, 64);
            s += __shfl_xor(s, 4, 64);
            s += __shfl_xor(s, 8, 64);
            if (c15 == 0) red[wm * 128 + m * 16 + quad * 4 + r][wn] = s;
        }
    __syncthreads();
    if (tid < 256)
        sig_part[(size_t)colBlk * MM + row0 + tid] =
            red[tid][0] + red[tid][1] + red[tid][2] + red[tid][3];
}

// ---------------- per-b softmax-style weights (64 blocks: 8 per b, full stats each)
__global__ __launch_bounds__(256) void softmax_k(const float* __restrict__ sig_part,
                                                 const float* __restrict__ imp,
                                                 float* __restrict__ a_ij) {
    int b = blockIdx.x >> 3, slice = blockIdx.x & 7;
    int tid = threadIdx.x;
    __shared__ float red[256];
    float sv[8];
    float m = -1e30f;
    #pragma unroll
    for (int p = 0; p < 8; ++p) {
        int n = p * 256 + tid;
        float s = 0.f;
        #pragma unroll
        for (int db = 0; db < 4; ++db) s += sig_part[db * MM + b * NN + n];
        sv[p] = s;
        m = fmaxf(m, s);
    }
    red[tid] = m; __syncthreads();
    for (int off = 128; off; off >>= 1) {
        if (tid < off) red[tid] = fmaxf(red[tid], red[tid + off]);
        __syncthreads();
    }
    m = red[0]; __syncthreads();
    float sum = 0.f;
    #pragma unroll
    for (int p = 0; p < 8; ++p) sum += expf(sv[p] - m);
    red[tid] = sum; __syncthreads();
    for (int off = 128; off; off >>= 1) {
        if (tid < off) red[tid] += red[tid + off];
        __syncthreads();
    }
    float inv = 1.f / (red[0] + 1e-9f * expf(-m));
    int n = slice * 256 + tid;
    a_ij[b * NN + n] = imp[b * NN + n] * expf(sv[slice] - m) * inv;
}

// ---------------- u partials from fp16 e_j: 1024 blocks, disjoint writes
__global__ __launch_bounds__(256) void u_kernel(const float* __restrict__ a_ij,
                                                const _Float16* __restrict__ eh,
                                                float* __restrict__ u_part) {
    int b = blockIdx.x >> 7, nc = blockIdx.x & 127;
    int t = threadIdx.x;
    float4 acc = {0.f, 0.f, 0.f, 0.f};
    const _Float16* base = eh + ((size_t)(b * NN + nc * 16)) * DD + t * 4;
    const float* ap = a_ij + b * NN + nc * 16;
    #pragma unroll
    for (int n = 0; n < 16; ++n) {
        float a = ap[n];
        half4 v = *(const half4*)(base + (size_t)n * DD);
        acc.x += a * (float)v[0]; acc.y += a * (float)v[1];
        acc.z += a * (float)v[2]; acc.w += a * (float)v[3];
    }
    *(float4*)(u_part + ((size_t)nc * BB + b) * DD + t * 4) = acc;
}

// ---------------- u[b,e] = sum over 128 partials
__global__ __launch_bounds__(256) void ureduce(const float* __restrict__ u_part,
                                               float* __restrict__ u) {
    int i = blockIdx.x * 256 + threadIdx.x;   // < 8192
    float s = 0.f;
    #pragma unroll 8
    for (int nc = 0; nc < 128; ++nc) s += u_part[(size_t)nc * BB * DD + i];
    u[i] = s;
}

// ---------------- A = X @ W^T with X cached in LDS; W read once (256 blocks)
__global__ __launch_bounds__(256) void rowdot8(const float* __restrict__ X,
                                               const float* __restrict__ W,
                                               float* __restrict__ out) {
    __shared__ float us[BB][DD];
    int tid = threadIdx.x;
    for (int i = tid; i < BB * DD / 4; i += 256)
        ((float4*)&us[0][0])[i] = ((const float4*)X)[i];
    __syncthreads();
    int w = tid >> 6, lane = tid & 63;
    int d = blockIdx.x * 4 + w;
    float acc[8] = {0.f, 0.f, 0.f, 0.f, 0.f, 0.f, 0.f, 0.f};
    for (int e0 = 0; e0 < DD; e0 += 256) {
        float4 wv = *(const float4*)&W[(size_t)d * DD + e0 + lane * 4];
        #pragma unroll
        for (int r = 0; r < 8; ++r) {
            float4 uv = *(const float4*)&us[r][e0 + lane * 4];
            acc[r] += wv.x * uv.x + wv.y * uv.y + wv.z * uv.z + wv.w * uv.w;
        }
    }
    #pragma unroll
    for (int r = 0; r < 8; ++r) {
        float s = acc[r];
        #pragma unroll
        for (int off = 32; off; off >>= 1) s += __shfl_down(s, off, 64);
        if (lane == 0) out[r * DD + d] = s;
    }
}

// ---------------- outputs: A, A_lk = A*R, A_l = A
__global__ __launch_bounds__(256) void out_kernel(const float* __restrict__ A,
                                                  const float* __restrict__ Rlk,
                                                  float* __restrict__ out) {
    int i = blockIdx.x * 256 + threadIdx.x;
    int d = i & (DD - 1);
    int l = (i >> 10) & (LL - 1);
    int b = i >> 17;
    out[BB * DD + i] = A[b * DD + d] * Rlk[l * DD + d];
    if (i < BB * DD) {
        out[i] = A[i];
        out[BB * DD + BB * LL * DD + i] = A[i];
    }
}

extern "C" void kernel_launch(void* const* d_in, const int* in_sizes, int n_in,
                              void* d_out, int out_size, void* d_ws, size_t ws_size,
                              hipStream_t stream) {
    const float* e_i   = (const float*)d_in[0];
    const float* e_j   = (const float*)d_in[1];
    const float* imp   = (const float*)d_in[2];
    const float* Rlk   = (const float*)d_in[3];
    const float* Wq    = (const float*)d_in[4];
    const float* Wk    = (const float*)d_in[5];
    const float* Wv    = (const float*)d_in[6];
    const float* omega = (const float*)d_in[7];
    float* out = (float*)d_out;
    float* ws  = (float*)d_ws;

    float* q    = ws;               // 8192
    float* sigp = ws + 8192;        // 65536 used (region holds 131072)
    float* a_ij = ws + 139264;      // 16384 (head reused as Abuf)
    float* u    = ws + 155648;      // 8192
    _Float16* eh = (_Float16*)(ws + 172032);      // MM*DD halfs = 32 MB
    _Float16* wh = eh + (size_t)MM * DD;          // 2 MB
    float* u_part = (float*)(wh + (size_t)DD * DD);  // 4 MB

    // 1) e_j -> fp16, Wk -> fp16, q = e_i @ Wq^T (Wq read once)
    prep_kernel<<<8960, 256, 0, stream>>>(e_j, eh, Wk, wh, e_i, Wq, q);

    // 2) sigma partials: m201-skeleton 8-phase 256^2 BK=64 pipeline, fused tanh-omega
    sigma256<<<dim3(256), 512, 0, stream>>>(eh, wh, q, omega, sigp);

    // 3) a_ij
    softmax_k<<<64, 256, 0, stream>>>(sigp, imp, a_ij);

    // 4) u partials (no atomics) from fp16 e_j, then reduce
    u_kernel<<<1024, 256, 0, stream>>>(a_ij, eh, u_part);
    ureduce<<<32, 256, 0, stream>>>(u_part, u);

    // 5) A = u @ Wv^T (Wv read once; Abuf = a_ij head)
    rowdot8<<<256, 256, 0, stream>>>(u, Wv, a_ij);

    // 6) outputs
    out_kernel<<<(BB * LL * DD) / 256, 256, 0, stream>>>(a_ij, Rlk, out);
}